// Round 11
// baseline (191.218 us; speedup 1.0000x reference)
//
#include <hip/hip_runtime.h>
#include <cstdint>

typedef unsigned short u16;
typedef __attribute__((ext_vector_type(8))) short short8;
typedef __attribute__((ext_vector_type(4))) short short4v;
typedef __attribute__((ext_vector_type(4))) float f32x4;
typedef __attribute__((ext_vector_type(4))) unsigned short u16x4;

__device__ __forceinline__ u16 f2bf(float x) {
    unsigned int u = __float_as_uint(x);
    u += 0x7fffu + ((u >> 16) & 1u);
    return (u16)(u >> 16);
}

__device__ __forceinline__ float fexp2(float x) {
#if __has_builtin(__builtin_amdgcn_exp2f)
    return __builtin_amdgcn_exp2f(x);
#else
    return exp2f(x);
#endif
}

// pack two rounded f32 -> bf16 pair in one dword (a low16, b high16) — proven path
__device__ __forceinline__ unsigned pack_bf16(float a, float b) {
    unsigned ua = __float_as_uint(a) + 0x8000u;
    unsigned ub = __float_as_uint(b) + 0x8000u;
    return __builtin_amdgcn_perm(ub, ua, 0x07060302u);
}

#if __has_builtin(__builtin_amdgcn_mfma_f32_16x16x16bf16_1k)
__device__ __forceinline__ f32x4 mfma16(short4v a, short4v b, f32x4 c) {
    return __builtin_amdgcn_mfma_f32_16x16x16bf16_1k(a, b, c, 0, 0, 0);
}
#else
__device__ __forceinline__ f32x4 mfma16(short4v a, short4v b, f32x4 c) {
    short8 a8 = {a[0], a[1], a[2], a[3], 0, 0, 0, 0};
    short8 b8 = {b[0], b[1], b[2], b[3], 0, 0, 0, 0};
    return __builtin_amdgcn_mfma_f32_16x16x32_bf16(a8, b8, c, 0, 0, 0);
}
#endif

__device__ __forceinline__ void gload_lds16(const u16* g, u16* l) {
    __builtin_amdgcn_global_load_lds(
        (const __attribute__((address_space(1))) void*)(g),
        (__attribute__((address_space(3))) void*)(l),
        16, 0, 0);
}

#define SBAR() do { __builtin_amdgcn_sched_barrier(0); \
                    __builtin_amdgcn_s_barrier(); \
                    __builtin_amdgcn_sched_barrier(0); } while (0)

// ---------------- fused prep: Wo transpose | cast x | Wq/Wk/Wv transposes ------
__global__ __launch_bounds__(256) void prep_kernel(
    const float* __restrict__ x,
    const float* __restrict__ Wq, const float* __restrict__ Wk,
    const float* __restrict__ Wv, const float* __restrict__ Wo,
    u16* __restrict__ xb, u16* __restrict__ wqkv, u16* __restrict__ wot)
{
    __shared__ u16 tile[64][65];
    const int z = blockIdx.z;
    const int tc = threadIdx.x & 63, tr = threadIdx.x >> 6;

    if (z == 1) {
        const int blk = blockIdx.y * 16 + blockIdx.x;
        const int base = (blk * 256 + threadIdx.x) * 4;
        #pragma unroll
        for (int i = 0; i < 16; ++i) {
            const int idx = base + i * 262144;
            float4 v = *(const float4*)(x + idx);
            u16x4 o;
            o.x = f2bf(v.x); o.y = f2bf(v.y); o.z = f2bf(v.z); o.w = f2bf(v.w);
            *(u16x4*)(xb + idx) = o;
        }
        return;
    }

    const float* src;
    u16* dst;
    int C, R, rb, cb;
    if (z == 0) {
        src = Wo; dst = wot; C = 1024; R = 1024;
        rb = blockIdx.x * 64; cb = blockIdx.y * 64;
    } else {
        const float* W = (z == 2) ? Wq : (z == 3) ? Wk : Wv;
        const int head = blockIdx.y;
        src = W + head * 65536;                                  // [1024][64]
        dst = wqkv + (size_t)(z - 2) * 1048576 + head * 65536;   // rows e, cols d
        C = 64; R = 1024;
        rb = blockIdx.x * 64; cb = 0;
    }
    #pragma unroll
    for (int i = 0; i < 64; i += 4)
        tile[tr + i][tc] = f2bf(src[(size_t)(rb + tr + i) * C + (cb + tc)]);
    __syncthreads();
    #pragma unroll
    for (int i = 0; i < 64; i += 4)
        dst[(size_t)(cb + tr + i) * R + (rb + tc)] = tile[tc][tr + i];
}

// ---------------- QKV GEMM v4: 256x192 tile, BK=64, 3-phase (R8/R9-proven) ----
__global__ __launch_bounds__(512, 2) void gemm_qkv_kernel(
    const u16* __restrict__ X, const u16* __restrict__ W,
    const float* __restrict__ bq, const float* __restrict__ bk,
    const float* __restrict__ bv,
    u16* __restrict__ qo, u16* __restrict__ ko, u16* __restrict__ vto)
{
    __shared__ __align__(16) u16 lds[57344];   // 112 KiB: 2 x [A 16384 | B 12288]
    const int tid = threadIdx.x;
    const int lane = tid & 63;
    const int wid = tid >> 6;            // 0..7
    const int wm = wid >> 2;             // 0..1  (128-row half)
    const int wn = wid & 3;              // 0..3  (48-col quarter)
    const int c = lane & 15, qd = lane >> 4;

    const int grp = blockIdx.x & 7, k = blockIdx.x >> 3;
    const int m0 = ((grp >> 1) * 4 + (k >> 3)) * 256;
    const int n0 = ((grp & 1) * 8 + (k & 7)) * 192;
    const u16* Xb = X + (size_t)m0 * 1024;
    const u16* Wb = W + (size_t)n0 * 1024;

    const int scg  = (tid & 7) ^ ((tid >> 3) & 7);  // staging source chunk
    const int srow = tid >> 3;                      // row within 64-row quarter
    const int co0 = (qd ^ (c & 7)) * 8;             // read chunk offset, ks=0
    const int co1 = ((4 + qd) ^ (c & 7)) * 8;       // ks=1
    const int rA = wm * 128 + c;
    const int rB = wn * 48 + c;

    auto stageA = [&](int t, int qa) {
        const int pb = (t & 1) * 28672;
        gload_lds16(Xb + (size_t)(qa * 64 + srow) * 1024 + t * 64 + scg * 8,
                    &lds[pb + (qa * 512 + tid) * 8]);
    };
    auto stageB = [&](int t, int qb) {
        const int pb = (t & 1) * 28672;
        gload_lds16(Wb + (size_t)(qb * 64 + srow) * 1024 + t * 64 + scg * 8,
                    &lds[pb + 16384 + (qb * 512 + tid) * 8]);
    };

    f32x4 acc[8][3];
    #pragma unroll
    for (int mi = 0; mi < 8; ++mi)
        #pragma unroll
        for (int ni = 0; ni < 3; ++ni) acc[mi][ni] = f32x4{0.f, 0.f, 0.f, 0.f};

    #pragma unroll
    for (int q = 0; q < 4; ++q) stageA(0, q);
    #pragma unroll
    for (int q = 0; q < 3; ++q) stageB(0, q);
    #pragma unroll
    for (int q = 0; q < 4; ++q) stageA(1, q);
    #pragma unroll
    for (int q = 0; q < 3; ++q) stageB(1, q);
    __builtin_amdgcn_s_waitcnt(0xF77);   // vmcnt(7): tile 0's 7 landed
    SBAR();

    #pragma unroll 2
    for (int t = 0; t < 16; ++t) {
        const int pb = (t & 1) * 28672;
        const u16* Al = &lds[pb];
        const u16* Bl = &lds[pb + 16384];

        // ---- Phase 1
        short8 af0[4][2], bf[3][2];
        #pragma unroll
        for (int mi = 0; mi < 4; ++mi) {
            af0[mi][0] = *(const short8*)&Al[(rA + mi * 16) * 64 + co0];
            af0[mi][1] = *(const short8*)&Al[(rA + mi * 16) * 64 + co1];
        }
        #pragma unroll
        for (int ni = 0; ni < 2; ++ni) {
            bf[ni][0] = *(const short8*)&Bl[(rB + ni * 16) * 64 + co0];
            bf[ni][1] = *(const short8*)&Bl[(rB + ni * 16) * 64 + co1];
        }
        SBAR();
        __builtin_amdgcn_s_setprio(1);
        #pragma unroll
        for (int mi = 0; mi < 4; ++mi)
            #pragma unroll
            for (int ni = 0; ni < 2; ++ni) {
                acc[mi][ni] = __builtin_amdgcn_mfma_f32_16x16x32_bf16(af0[mi][0], bf[ni][0], acc[mi][ni], 0, 0, 0);
                acc[mi][ni] = __builtin_amdgcn_mfma_f32_16x16x32_bf16(af0[mi][1], bf[ni][1], acc[mi][ni], 0, 0, 0);
            }
        __builtin_amdgcn_s_setprio(0);
        SBAR();

        // ---- Phase 2
        short8 af1[4][2];
        #pragma unroll
        for (int mi = 0; mi < 4; ++mi) {
            af1[mi][0] = *(const short8*)&Al[(rA + (mi + 4) * 16) * 64 + co0];
            af1[mi][1] = *(const short8*)&Al[(rA + (mi + 4) * 16) * 64 + co1];
        }
        bf[2][0] = *(const short8*)&Bl[(rB + 2 * 16) * 64 + co0];
        bf[2][1] = *(const short8*)&Bl[(rB + 2 * 16) * 64 + co1];
        if (t < 14) { stageA(t + 2, 0); stageA(t + 2, 2); }
        SBAR();
        __builtin_amdgcn_s_setprio(1);
        #pragma unroll
        for (int mi = 0; mi < 4; ++mi) {
            acc[mi][2] = __builtin_amdgcn_mfma_f32_16x16x32_bf16(af0[mi][0], bf[2][0], acc[mi][2], 0, 0, 0);
            acc[mi][2] = __builtin_amdgcn_mfma_f32_16x16x32_bf16(af0[mi][1], bf[2][1], acc[mi][2], 0, 0, 0);
        }
        #pragma unroll
        for (int mi = 0; mi < 4; ++mi) {
            acc[mi + 4][0] = __builtin_amdgcn_mfma_f32_16x16x32_bf16(af1[mi][0], bf[0][0], acc[mi + 4][0], 0, 0, 0);
            acc[mi + 4][0] = __builtin_amdgcn_mfma_f32_16x16x32_bf16(af1[mi][1], bf[0][1], acc[mi + 4][0], 0, 0, 0);
        }
        __builtin_amdgcn_s_setprio(0);
        SBAR();

        // ---- Phase 3
        if (t < 14) {
            stageA(t + 2, 1); stageA(t + 2, 3);
            stageB(t + 2, 0); stageB(t + 2, 1); stageB(t + 2, 2);
        }
        SBAR();
        __builtin_amdgcn_s_setprio(1);
        #pragma unroll
        for (int mi = 0; mi < 4; ++mi)
            #pragma unroll
            for (int ni = 1; ni < 3; ++ni) {
                acc[mi + 4][ni] = __builtin_amdgcn_mfma_f32_16x16x32_bf16(af1[mi][0], bf[ni][0], acc[mi + 4][ni], 0, 0, 0);
                acc[mi + 4][ni] = __builtin_amdgcn_mfma_f32_16x16x32_bf16(af1[mi][1], bf[ni][1], acc[mi + 4][ni], 0, 0, 0);
            }
        __builtin_amdgcn_s_setprio(0);
        if (t < 14)       __builtin_amdgcn_s_waitcnt(0xF77);   // vmcnt(7)
        else if (t == 14) __builtin_amdgcn_s_waitcnt(0xF70);   // vmcnt(0): last
        SBAR();
    }

    // epilogue: n -> (mat, h, e); m -> (b, s)   [R8/R9-proven per-element]
    #pragma unroll
    for (int mi = 0; mi < 8; ++mi) {
        const int mbase = m0 + wm * 128 + mi * 16 + qd * 4;
        const int b = mbase >> 11;
        #pragma unroll
        for (int ni = 0; ni < 3; ++ni) {
            const int n = n0 + wn * 48 + ni * 16 + c;
            const int mat = n >> 10;
            const int idx = n & 1023;
            const int h = idx >> 6, e = idx & 63;
            const float bias = (mat == 0 ? bq : (mat == 1 ? bk : bv))[idx];
            if (mat == 2) {
                const int s = mbase & 2047;
                u16x4 pv;
                pv.x = f2bf(acc[mi][ni][0] + bias);
                pv.y = f2bf(acc[mi][ni][1] + bias);
                pv.z = f2bf(acc[mi][ni][2] + bias);
                pv.w = f2bf(acc[mi][ni][3] + bias);
                *(u16x4*)(vto + ((((size_t)(b * 16 + h) * 128 + (s >> 4)) * 64 + e) * 16
                                 + (s & 15))) = pv;
            } else {
                const float scale = (mat == 0) ? 0.18033688011112042f : 1.0f;
                u16* dst = (mat == 0) ? qo : ko;
                #pragma unroll
                for (int r = 0; r < 4; ++r) {
                    const int s = (mbase + r) & 2047;
                    dst[((size_t)((b * 16 + h) * 2048 + s)) * 64 + e] =
                        f2bf((acc[mi][ni][r] + bias) * scale);
                }
            }
        }
    }
}

// ---------------- flash attention v11: v8 body, templated q-tile height -------
// R2 fit: phase1 768 blocks @30.7us, phase2 256 LONE blocks @22.7us (1/CU, no
// latency hiding) -> ~12us idle-CU waste. Dynamic fixes (R3/R4) broke locality/
// phase-sync. v11 is the STATIC fix: grid 1280 = 768 full 64-row tiles (qt
// 0..23, mapping identical to v8) + 512 half 32-row tiles (qt 24..31 split in
// two). Half-blocks backfill as full blocks drain: tail runs 512 blocks at
// 2/CU instead of 256 at 1/CU. bh formula unchanged (768%8==0 keeps the XCD
// round-robin phase) -> locality identical; no atomics -> no desync.
// flash_impl<QB>: QB scales ONLY the q-dimension arrays/loops; K/V staging,
// ring-3, vmcnt(4) discipline byte-identical to the proven v8.
template<int QB>
__device__ __forceinline__ void flash_impl(
    const u16* __restrict__ Qh, const u16* __restrict__ Kh,
    const u16* __restrict__ Vh, u16* __restrict__ ctx,
    int b, int h, int q0, char* pool,
    int tid, int lane, int w, int c, int qd)
{
    u16* stage = (u16*)pool;                              // K ring-3: 4w*3072 u16
    float (*Os)[64][66] = (float (*)[64][66])pool;        // merge (aliased)
    float (*Ls)[64] = (float (*)[64])(pool + 33792);      // 1 KB

    u16* Kst = stage + w * 3072;             // 3 K slots x 1024 u16

    const int krow8 = lane >> 3;
    const int kgc = (lane & 7) ^ (krow8 & 7);
    const int voff = c * 16 + qd * 4;

    short8 qf[QB][2];
    #pragma unroll
    for (int qb = 0; qb < QB; ++qb)
        #pragma unroll
        for (int kb = 0; kb < 2; ++kb)
            qf[qb][kb] = *(const short8*)&Qh[(size_t)(q0 + qb * 16 + c) * 64 + kb * 32 + qd * 8];

    f32x4 o[4][QB];
    float lsum[QB];
    #pragma unroll
    for (int mt = 0; mt < 4; ++mt)
        #pragma unroll
        for (int qb = 0; qb < QB; ++qb) o[mt][qb] = f32x4{0.f, 0.f, 0.f, 0.f};
    #pragma unroll
    for (int qb = 0; qb < QB; ++qb) lsum[qb] = 0.f;

    #pragma unroll
    for (int j = 0; j < 2; ++j) {
        const int row = j * 8 + krow8;
        gload_lds16(Kh + (size_t)(w * 512 + row) * 64 + kgc * 8,
                    Kst + j * 512 + lane * 8);
    }
    short4v vA[4], vB[4];
    {
        const u16* vb = Vh + (size_t)(w * 32) * 1024 + voff;
        #pragma unroll
        for (int mt = 0; mt < 4; ++mt)
            vA[mt] = *(const short4v*)(vb + mt * 256);
    }
    #pragma unroll
    for (int j = 0; j < 2; ++j) {
        const int row = j * 8 + krow8;
        gload_lds16(Kh + (size_t)(w * 512 + 16 + row) * 64 + kgc * 8,
                    Kst + 1024 + j * 512 + lane * 8);
    }

    int cur = 0;
    auto body = [&](int it, short4v (&VC)[4], short4v (&VN)[4]) {
        u16* Kb = Kst + cur * 1024;

        __builtin_amdgcn_s_waitcnt(0xF74);   // vmcnt(4): K(it) staged
        __builtin_amdgcn_sched_barrier(0);

        short8 kf[2];
        #pragma unroll
        for (int kb = 0; kb < 2; ++kb)
            kf[kb] = *(const short8*)&Kb[c * 64 + ((4 * kb + qd) ^ (c & 7)) * 8];

        __builtin_amdgcn_sched_barrier(0);

        {
            const int itn = (it + 1) & 31;
            const u16* vb = Vh + (size_t)(w * 32 + itn) * 1024 + voff;
            #pragma unroll
            for (int mt = 0; mt < 4; ++mt)
                VN[mt] = *(const short4v*)(vb + mt * 256);
        }
        {
            const int itn = (it + 2) & 31;
            const int t0n = w * 512 + itn * 16;
            const int nslot = (cur >= 1) ? cur - 1 : 2;
            u16* Kn = Kst + nslot * 1024;
            #pragma unroll
            for (int j = 0; j < 2; ++j) {
                const int row = j * 8 + krow8;
                gload_lds16(Kh + (size_t)(t0n + row) * 64 + kgc * 8,
                            Kn + j * 512 + lane * 8);
            }
        }

        f32x4 sc[QB];
        #pragma unroll
        for (int qb = 0; qb < QB; ++qb) {
            sc[qb] = f32x4{0.f, 0.f, 0.f, 0.f};
            sc[qb] = __builtin_amdgcn_mfma_f32_16x16x32_bf16(kf[0], qf[qb][0], sc[qb], 0, 0, 0);
            sc[qb] = __builtin_amdgcn_mfma_f32_16x16x32_bf16(kf[1], qf[qb][1], sc[qb], 0, 0, 0);
        }

        short4v pb[QB];
        #pragma unroll
        for (int qb = 0; qb < QB; ++qb) {
            float p0 = fexp2(sc[qb][0]);
            float p1 = fexp2(sc[qb][1]);
            float p2 = fexp2(sc[qb][2]);
            float p3 = fexp2(sc[qb][3]);
            lsum[qb] += (p0 + p1) + (p2 + p3);
            unsigned d0 = pack_bf16(p0, p1);
            unsigned d1 = pack_bf16(p2, p3);
            union { unsigned u[2]; short4v s; } pu;
            pu.u[0] = d0; pu.u[1] = d1;
            pb[qb] = pu.s;
        }

        #pragma unroll
        for (int qb = 0; qb < QB; ++qb)
            #pragma unroll
            for (int mt = 0; mt < 4; ++mt)
                o[mt][qb] = mfma16(VC[mt], pb[qb], o[mt][qb]);

        cur = (cur == 2) ? 0 : cur + 1;
    };

    for (int it2 = 0; it2 < 16; ++it2) {
        body(2 * it2, vA, vB);
        body(2 * it2 + 1, vB, vA);
    }

    __builtin_amdgcn_s_waitcnt(0xF70);   // vmcnt(0) before aliasing the pool
    __syncthreads();

    #pragma unroll
    for (int qb = 0; qb < QB; ++qb) {
        lsum[qb] += __shfl_xor(lsum[qb], 16, 64);
        lsum[qb] += __shfl_xor(lsum[qb], 32, 64);
    }
    if (qd == 0) {
        #pragma unroll
        for (int qb = 0; qb < QB; ++qb) Ls[w][qb * 16 + c] = lsum[qb];
    }

    if (w >= 2) {
        float (*S)[66] = Os[w - 2];
        #pragma unroll
        for (int mt = 0; mt < 4; ++mt)
            #pragma unroll
            for (int qb = 0; qb < QB; ++qb)
                #pragma unroll
                for (int r = 0; r < 4; ++r)
                    S[mt * 16 + qd * 4 + r][qb * 16 + c] = o[mt][qb][r];
    }
    __syncthreads();
    if (w < 2) {
        float (*S)[66] = Os[w];
        #pragma unroll
        for (int mt = 0; mt < 4; ++mt)
            #pragma unroll
            for (int qb = 0; qb < QB; ++qb)
                #pragma unroll
                for (int r = 0; r < 4; ++r)
                    o[mt][qb][r] += S[mt * 16 + qd * 4 + r][qb * 16 + c];
    }
    __syncthreads();
    if (w == 1) {
        float (*S)[66] = Os[0];
        #pragma unroll
        for (int mt = 0; mt < 4; ++mt)
            #pragma unroll
            for (int qb = 0; qb < QB; ++qb)
                #pragma unroll
                for (int r = 0; r < 4; ++r)
                    S[mt * 16 + qd * 4 + r][qb * 16 + c] = o[mt][qb][r];
    }
    __syncthreads();
    if (w == 0) {
        float (*S)[66] = Os[0];
        float inv[QB];
        #pragma unroll
        for (int qb = 0; qb < QB; ++qb) {
            int q = qb * 16 + c;
            float l = (Ls[0][q] + Ls[1][q]) + (Ls[2][q] + Ls[3][q]);
            inv[qb] = __builtin_amdgcn_rcpf(l);
        }
        #pragma unroll
        for (int mt = 0; mt < 4; ++mt)
            #pragma unroll
            for (int qb = 0; qb < QB; ++qb) {
                u16x4 ov;
                #pragma unroll
                for (int r = 0; r < 4; ++r) {
                    float v = (o[mt][qb][r] + S[mt * 16 + qd * 4 + r][qb * 16 + c]) * inv[qb];
                    ((u16*)&ov)[r] = f2bf(v);
                }
                *(u16x4*)&ctx[((size_t)(b * 2048 + q0 + qb * 16 + c)) * 1024
                              + h * 64 + mt * 16 + qd * 4] = ov;
            }
    }
}

__global__ __launch_bounds__(256, 3) void flash_kernel(
    const u16* __restrict__ Q,   // [32][2048][64], pre-scaled by 0.125*log2e
    const u16* __restrict__ K,   // [32][2048][64]
    const u16* __restrict__ V2,  // [32][128][64][16]
    u16* __restrict__ ctx)       // [4096][1024] = [b*2048+s][h*64+e]
{
    __shared__ __align__(16) char pool[34816];
    const int tid = threadIdx.x, lane = tid & 63, w = tid >> 6;
    const int c = lane & 15, qd = lane >> 4;
    const int bid = blockIdx.x;

    if (bid < 768) {
        // full 64-row q-tiles: qt 0..23, mapping identical to proven v8
        const int r5 = bid & 31;
        const int bh = (r5 & 7) * 4 + (r5 >> 3);
        const int q0 = (bid >> 5) * 64;
        flash_impl<4>(Q + (size_t)bh * 131072, K + (size_t)bh * 131072,
                      V2 + (size_t)bh * 131072, ctx,
                      bh >> 4, bh & 15, q0, pool, tid, lane, w, c, qd);
    } else {
        // half 32-row q-tiles covering qt 24..31
        const int hid = bid - 768;               // 0..511; hid&7 == bid&7 (768%8==0)
        const int r5 = hid & 31;
        const int bh = (r5 & 7) * 4 + (r5 >> 3);
        const int rest = hid >> 5;               // 0..15
        const int q0 = (24 + (rest >> 1)) * 64 + (rest & 1) * 32;
        flash_impl<2>(Q + (size_t)bh * 131072, K + (size_t)bh * 131072,
                      V2 + (size_t)bh * 131072, ctx,
                      bh >> 4, bh & 15, q0, pool, tid, lane, w, c, qd);
    }
}

// ---------------- output projection v2 (R9-proven verbatim) -------------------
__global__ __launch_bounds__(256, 4) void gemm_out_kernel(
    const u16* __restrict__ A, const u16* __restrict__ Wt,
    const float* __restrict__ bo, float* __restrict__ out)
{
    __shared__ __align__(16) u16 As[2][64 * 32];
    __shared__ __align__(16) u16 Bs[2][128 * 32];
    const int tid = threadIdx.x;
    const int lane = tid & 63;
    const int wv = tid >> 6;
    const int wm = wv & 1, wn = wv >> 1;
    const int c = lane & 15, qd = lane >> 4;

    const int id = (blockIdx.x & 7) * 64 + (blockIdx.x >> 3);
    const int m0 = (id >> 3) * 64;
    const int n0 = (id & 7) * 128;

    f32x4 acc[2][4];
    #pragma unroll
    for (int a = 0; a < 2; ++a)
        #pragma unroll
        for (int b2 = 0; b2 < 4; ++b2) acc[a][b2] = f32x4{0.f, 0.f, 0.f, 0.f};

    const u16* Ab = A + (size_t)m0 * 1024;
    const u16* Wb = Wt + (size_t)n0 * 1024;

    const int arow = tid >> 2, apart = tid & 3;

    auto stage = [&](int t, int p) {
        gload_lds16(Ab + (size_t)arow * 1024 + t * 32 + apart * 8, &As[p][tid * 8]);
        #pragma unroll
        for (int i = 0; i < 2; ++i) {
            int slot = i * 256 + tid;
            int row = slot >> 2, part = slot & 3;
            gload_lds16(Wb + (size_t)row * 1024 + t * 32 + part * 8, &Bs[p][slot * 8]);
        }
    };

    stage(0, 0);

    for (int t = 0; t < 32; ++t) {
        const int p = t & 1;
        if (t < 31) stage(t + 1, p ^ 1);
        __builtin_amdgcn_sched_barrier(0);
        if (t < 31) __builtin_amdgcn_s_waitcnt(0xF73);   // vmcnt(3): tile t landed
        else        __builtin_amdgcn_s_waitcnt(0xF70);   // last tile: drain
        SBAR();
        short8 af[2], bf[4];
        #pragma unroll
        for (int mt = 0; mt < 2; ++mt)
            af[mt] = *(const short8*)&As[p][(wm * 32 + mt * 16 + c) * 32 + qd * 8];
        #pragma unroll
        for (int nt = 0; nt < 4; ++nt)
            bf[nt] = *(const short8*)&Bs[p][(wn * 64 + nt * 16 + c) * 32 + qd * 8];
        __builtin_amdgcn_s_setprio(1);
        #pragma unroll
        for (int mt = 0; mt < 2; ++mt)
            #pragma unroll
            for (int nt = 0; nt < 4; ++nt)
                acc[mt][nt] = __builtin_amdgcn_mfma_f32_16x16x32_bf16(af[mt], bf[nt], acc[mt][nt], 0, 0, 0);
        __builtin_amdgcn_s_setprio(0);
        SBAR();   // all reads of buf p done before it is re-staged at t+2
    }

    #pragma unroll
    for (int mt = 0; mt < 2; ++mt) {
        const int mbase = m0 + wm * 32 + mt * 16 + qd * 4;
        #pragma unroll
        for (int nt = 0; nt < 4; ++nt) {
            const int n = n0 + wn * 64 + nt * 16 + c;
            const float bias = bo[n];
            #pragma unroll
            for (int r = 0; r < 4; ++r)
                out[(size_t)(mbase + r) * 1024 + n] = acc[mt][nt][r] + bias;
        }
    }
}

extern "C" void kernel_launch(void* const* d_in, const int* in_sizes, int n_in,
                              void* d_out, int out_size, void* d_ws, size_t ws_size,
                              hipStream_t stream) {
    const float* x  = (const float*)d_in[0];
    const float* Wq = (const float*)d_in[1];
    const float* bq = (const float*)d_in[2];
    const float* Wk = (const float*)d_in[3];
    const float* bk = (const float*)d_in[4];
    const float* Wv = (const float*)d_in[5];
    const float* bv = (const float*)d_in[6];
    const float* Wo = (const float*)d_in[7];
    const float* bo = (const float*)d_in[8];
    float* out = (float*)d_out;

    u16* ws    = (u16*)d_ws;
    u16* xb    = ws;                          // 4096*1024
    u16* wqkv  = xb + 4096 * 1024;            // 3072*1024
    u16* wot   = wqkv + 3072 * 1024;          // 1024*1024
    u16* qws   = wot + 1024 * 1024;           // 32*2048*64
    u16* kws   = qws + 4194304;               // 32*2048*64
    u16* v2ws  = kws + 4194304;               // 32*128*64*16
    u16* ctxws = v2ws + 4194304;              // 4096*1024

    prep_kernel<<<dim3(16, 16, 5), 256, 0, stream>>>(x, Wq, Wk, Wv, Wo, xb, wqkv, wot);
    gemm_qkv_kernel<<<256, 512, 0, stream>>>(xb, wqkv, bq, bk, bv, qws, kws, v2ws);
    flash_kernel<<<1280, 256, 0, stream>>>(qws, kws, v2ws, ctxws);
    gemm_out_kernel<<<512, 256, 0, stream>>>(ctxws, wot, bo, out);
}

// Round 12
// 186.523 us; speedup vs baseline: 1.0252x; 1.0252x over previous
//
#include <hip/hip_runtime.h>
#include <cstdint>

typedef unsigned short u16;
typedef __attribute__((ext_vector_type(8))) short short8;
typedef __attribute__((ext_vector_type(4))) short short4v;
typedef __attribute__((ext_vector_type(4))) float f32x4;
typedef __attribute__((ext_vector_type(4))) unsigned short u16x4;

__device__ __forceinline__ u16 f2bf(float x) {
    unsigned int u = __float_as_uint(x);
    u += 0x7fffu + ((u >> 16) & 1u);
    return (u16)(u >> 16);
}

__device__ __forceinline__ float fexp2(float x) {
#if __has_builtin(__builtin_amdgcn_exp2f)
    return __builtin_amdgcn_exp2f(x);
#else
    return exp2f(x);
#endif
}

// pack two rounded f32 -> bf16 pair in one dword (a low16, b high16) — proven path
__device__ __forceinline__ unsigned pack_bf16(float a, float b) {
    unsigned ua = __float_as_uint(a) + 0x8000u;
    unsigned ub = __float_as_uint(b) + 0x8000u;
    return __builtin_amdgcn_perm(ub, ua, 0x07060302u);
}

#if __has_builtin(__builtin_amdgcn_mfma_f32_16x16x16bf16_1k)
__device__ __forceinline__ f32x4 mfma16(short4v a, short4v b, f32x4 c) {
    return __builtin_amdgcn_mfma_f32_16x16x16bf16_1k(a, b, c, 0, 0, 0);
}
#else
__device__ __forceinline__ f32x4 mfma16(short4v a, short4v b, f32x4 c) {
    short8 a8 = {a[0], a[1], a[2], a[3], 0, 0, 0, 0};
    short8 b8 = {b[0], b[1], b[2], b[3], 0, 0, 0, 0};
    return __builtin_amdgcn_mfma_f32_16x16x32_bf16(a8, b8, c, 0, 0, 0);
}
#endif

__device__ __forceinline__ void gload_lds16(const u16* g, u16* l) {
    __builtin_amdgcn_global_load_lds(
        (const __attribute__((address_space(1))) void*)(g),
        (__attribute__((address_space(3))) void*)(l),
        16, 0, 0);
}

#define SBAR() do { __builtin_amdgcn_sched_barrier(0); \
                    __builtin_amdgcn_s_barrier(); \
                    __builtin_amdgcn_sched_barrier(0); } while (0)

// ---------------- fused prep: Wo transpose | cast x | Wq/Wk/Wv transposes ------
__global__ __launch_bounds__(256) void prep_kernel(
    const float* __restrict__ x,
    const float* __restrict__ Wq, const float* __restrict__ Wk,
    const float* __restrict__ Wv, const float* __restrict__ Wo,
    u16* __restrict__ xb, u16* __restrict__ wqkv, u16* __restrict__ wot)
{
    __shared__ u16 tile[64][65];
    const int z = blockIdx.z;
    const int tc = threadIdx.x & 63, tr = threadIdx.x >> 6;

    if (z == 1) {
        const int blk = blockIdx.y * 16 + blockIdx.x;
        const int base = (blk * 256 + threadIdx.x) * 4;
        #pragma unroll
        for (int i = 0; i < 16; ++i) {
            const int idx = base + i * 262144;
            float4 v = *(const float4*)(x + idx);
            u16x4 o;
            o.x = f2bf(v.x); o.y = f2bf(v.y); o.z = f2bf(v.z); o.w = f2bf(v.w);
            *(u16x4*)(xb + idx) = o;
        }
        return;
    }

    const float* src;
    u16* dst;
    int C, R, rb, cb;
    if (z == 0) {
        src = Wo; dst = wot; C = 1024; R = 1024;
        rb = blockIdx.x * 64; cb = blockIdx.y * 64;
    } else {
        const float* W = (z == 2) ? Wq : (z == 3) ? Wk : Wv;
        const int head = blockIdx.y;
        src = W + head * 65536;                                  // [1024][64]
        dst = wqkv + (size_t)(z - 2) * 1048576 + head * 65536;   // rows e, cols d
        C = 64; R = 1024;
        rb = blockIdx.x * 64; cb = 0;
    }
    #pragma unroll
    for (int i = 0; i < 64; i += 4)
        tile[tr + i][tc] = f2bf(src[(size_t)(rb + tr + i) * C + (cb + tc)]);
    __syncthreads();
    #pragma unroll
    for (int i = 0; i < 64; i += 4)
        dst[(size_t)(cb + tr + i) * R + (rb + tc)] = tile[tc][tr + i];
}

// ---------------- QKV GEMM v4: 256x192 tile, BK=64, 3-phase (R8/R9-proven) ----
__global__ __launch_bounds__(512, 2) void gemm_qkv_kernel(
    const u16* __restrict__ X, const u16* __restrict__ W,
    const float* __restrict__ bq, const float* __restrict__ bk,
    const float* __restrict__ bv,
    u16* __restrict__ qo, u16* __restrict__ ko, u16* __restrict__ vto)
{
    __shared__ __align__(16) u16 lds[57344];   // 112 KiB: 2 x [A 16384 | B 12288]
    const int tid = threadIdx.x;
    const int lane = tid & 63;
    const int wid = tid >> 6;            // 0..7
    const int wm = wid >> 2;             // 0..1  (128-row half)
    const int wn = wid & 3;              // 0..3  (48-col quarter)
    const int c = lane & 15, qd = lane >> 4;

    const int grp = blockIdx.x & 7, k = blockIdx.x >> 3;
    const int m0 = ((grp >> 1) * 4 + (k >> 3)) * 256;
    const int n0 = ((grp & 1) * 8 + (k & 7)) * 192;
    const u16* Xb = X + (size_t)m0 * 1024;
    const u16* Wb = W + (size_t)n0 * 1024;

    const int scg  = (tid & 7) ^ ((tid >> 3) & 7);  // staging source chunk
    const int srow = tid >> 3;                      // row within 64-row quarter
    const int co0 = (qd ^ (c & 7)) * 8;             // read chunk offset, ks=0
    const int co1 = ((4 + qd) ^ (c & 7)) * 8;       // ks=1
    const int rA = wm * 128 + c;
    const int rB = wn * 48 + c;

    auto stageA = [&](int t, int qa) {
        const int pb = (t & 1) * 28672;
        gload_lds16(Xb + (size_t)(qa * 64 + srow) * 1024 + t * 64 + scg * 8,
                    &lds[pb + (qa * 512 + tid) * 8]);
    };
    auto stageB = [&](int t, int qb) {
        const int pb = (t & 1) * 28672;
        gload_lds16(Wb + (size_t)(qb * 64 + srow) * 1024 + t * 64 + scg * 8,
                    &lds[pb + 16384 + (qb * 512 + tid) * 8]);
    };

    f32x4 acc[8][3];
    #pragma unroll
    for (int mi = 0; mi < 8; ++mi)
        #pragma unroll
        for (int ni = 0; ni < 3; ++ni) acc[mi][ni] = f32x4{0.f, 0.f, 0.f, 0.f};

    #pragma unroll
    for (int q = 0; q < 4; ++q) stageA(0, q);
    #pragma unroll
    for (int q = 0; q < 3; ++q) stageB(0, q);
    #pragma unroll
    for (int q = 0; q < 4; ++q) stageA(1, q);
    #pragma unroll
    for (int q = 0; q < 3; ++q) stageB(1, q);
    __builtin_amdgcn_s_waitcnt(0xF77);   // vmcnt(7): tile 0's 7 landed
    SBAR();

    #pragma unroll 2
    for (int t = 0; t < 16; ++t) {
        const int pb = (t & 1) * 28672;
        const u16* Al = &lds[pb];
        const u16* Bl = &lds[pb + 16384];

        // ---- Phase 1
        short8 af0[4][2], bf[3][2];
        #pragma unroll
        for (int mi = 0; mi < 4; ++mi) {
            af0[mi][0] = *(const short8*)&Al[(rA + mi * 16) * 64 + co0];
            af0[mi][1] = *(const short8*)&Al[(rA + mi * 16) * 64 + co1];
        }
        #pragma unroll
        for (int ni = 0; ni < 2; ++ni) {
            bf[ni][0] = *(const short8*)&Bl[(rB + ni * 16) * 64 + co0];
            bf[ni][1] = *(const short8*)&Bl[(rB + ni * 16) * 64 + co1];
        }
        SBAR();
        __builtin_amdgcn_s_setprio(1);
        #pragma unroll
        for (int mi = 0; mi < 4; ++mi)
            #pragma unroll
            for (int ni = 0; ni < 2; ++ni) {
                acc[mi][ni] = __builtin_amdgcn_mfma_f32_16x16x32_bf16(af0[mi][0], bf[ni][0], acc[mi][ni], 0, 0, 0);
                acc[mi][ni] = __builtin_amdgcn_mfma_f32_16x16x32_bf16(af0[mi][1], bf[ni][1], acc[mi][ni], 0, 0, 0);
            }
        __builtin_amdgcn_s_setprio(0);
        SBAR();

        // ---- Phase 2
        short8 af1[4][2];
        #pragma unroll
        for (int mi = 0; mi < 4; ++mi) {
            af1[mi][0] = *(const short8*)&Al[(rA + (mi + 4) * 16) * 64 + co0];
            af1[mi][1] = *(const short8*)&Al[(rA + (mi + 4) * 16) * 64 + co1];
        }
        bf[2][0] = *(const short8*)&Bl[(rB + 2 * 16) * 64 + co0];
        bf[2][1] = *(const short8*)&Bl[(rB + 2 * 16) * 64 + co1];
        if (t < 14) { stageA(t + 2, 0); stageA(t + 2, 2); }
        SBAR();
        __builtin_amdgcn_s_setprio(1);
        #pragma unroll
        for (int mi = 0; mi < 4; ++mi) {
            acc[mi][2] = __builtin_amdgcn_mfma_f32_16x16x32_bf16(af0[mi][0], bf[2][0], acc[mi][2], 0, 0, 0);
            acc[mi][2] = __builtin_amdgcn_mfma_f32_16x16x32_bf16(af0[mi][1], bf[2][1], acc[mi][2], 0, 0, 0);
        }
        #pragma unroll
        for (int mi = 0; mi < 4; ++mi) {
            acc[mi + 4][0] = __builtin_amdgcn_mfma_f32_16x16x32_bf16(af1[mi][0], bf[0][0], acc[mi + 4][0], 0, 0, 0);
            acc[mi + 4][0] = __builtin_amdgcn_mfma_f32_16x16x32_bf16(af1[mi][1], bf[0][1], acc[mi + 4][0], 0, 0, 0);
        }
        __builtin_amdgcn_s_setprio(0);
        SBAR();

        // ---- Phase 3
        if (t < 14) {
            stageA(t + 2, 1); stageA(t + 2, 3);
            stageB(t + 2, 0); stageB(t + 2, 1); stageB(t + 2, 2);
        }
        SBAR();
        __builtin_amdgcn_s_setprio(1);
        #pragma unroll
        for (int mi = 0; mi < 4; ++mi)
            #pragma unroll
            for (int ni = 1; ni < 3; ++ni) {
                acc[mi + 4][ni] = __builtin_amdgcn_mfma_f32_16x16x32_bf16(af1[mi][0], bf[ni][0], acc[mi + 4][ni], 0, 0, 0);
                acc[mi + 4][ni] = __builtin_amdgcn_mfma_f32_16x16x32_bf16(af1[mi][1], bf[ni][1], acc[mi + 4][ni], 0, 0, 0);
            }
        __builtin_amdgcn_s_setprio(0);
        if (t < 14)       __builtin_amdgcn_s_waitcnt(0xF77);   // vmcnt(7)
        else if (t == 14) __builtin_amdgcn_s_waitcnt(0xF70);   // vmcnt(0): last
        SBAR();
    }

    // epilogue: n -> (mat, h, e); m -> (b, s)
    #pragma unroll
    for (int mi = 0; mi < 8; ++mi) {
        const int mbase = m0 + wm * 128 + mi * 16 + qd * 4;
        const int b = mbase >> 11;
        #pragma unroll
        for (int ni = 0; ni < 3; ++ni) {
            const int n = n0 + wn * 48 + ni * 16 + c;
            const int mat = n >> 10;
            const int idx = n & 1023;
            const int h = idx >> 6, e = idx & 63;
            const float bias = (mat == 0 ? bq : (mat == 1 ? bk : bv))[idx];
            if (mat == 2) {
                const int s = mbase & 2047;
                u16x4 pv;
                pv.x = f2bf(acc[mi][ni][0] + bias);
                pv.y = f2bf(acc[mi][ni][1] + bias);
                pv.z = f2bf(acc[mi][ni][2] + bias);
                pv.w = f2bf(acc[mi][ni][3] + bias);
                *(u16x4*)(vto + ((((size_t)(b * 16 + h) * 128 + (s >> 4)) * 64 + e) * 16
                                 + (s & 15))) = pv;
            } else {
                const float scale = (mat == 0) ? 0.18033688011112042f : 1.0f;
                u16* dst = (mat == 0) ? qo : ko;
                #pragma unroll
                for (int r = 0; r < 4; ++r) {
                    const int s = (mbase + r) & 2047;
                    dst[((size_t)((b * 16 + h) * 2048 + s)) * 64 + e] =
                        f2bf((acc[mi][ni][r] + bias) * scale);
                }
            }
        }
    }
}

// ---------------- flash attention v8 (proven 52.9-54.6 us, verbatim) ----------
__global__ __launch_bounds__(256, 3) void flash_kernel(
    const u16* __restrict__ Q,   // [32][2048][64], pre-scaled by 0.125*log2e
    const u16* __restrict__ K,   // [32][2048][64]
    const u16* __restrict__ V2,  // [32][128][64][16]
    u16* __restrict__ ctx)       // [4096][1024] = [b*2048+s][h*64+e]
{
    __shared__ __align__(16) char pool[34816];
    u16* stage = (u16*)pool;                              // K ring-3: 4w*3072 u16
    float (*Os)[64][66] = (float (*)[64][66])pool;        // merge (aliased)
    float (*Ls)[64] = (float (*)[64])(pool + 33792);      // 1 KB

    const int tid = threadIdx.x, lane = tid & 63, w = tid >> 6;
    const int c = lane & 15, qd = lane >> 4;
    const int bid = blockIdx.x;
    const int r5 = bid & 31;
    const int bh = (r5 & 7) * 4 + (r5 >> 3);   // pin each bh's blocks to one XCD
    const int q0 = (bid >> 5) * 64;
    const int b = bh >> 4, h = bh & 15;
    const u16* Qh = Q + (size_t)bh * 2048 * 64;
    const u16* Kh = K + (size_t)bh * 2048 * 64;
    const u16* Vh = V2 + (size_t)bh * 128 * 1024;

    u16* Kst = stage + w * 3072;             // 3 K slots x 1024 u16

    const int krow8 = lane >> 3;
    const int kgc = (lane & 7) ^ (krow8 & 7);
    const int voff = c * 16 + qd * 4;

    short8 qf[4][2];
    #pragma unroll
    for (int qb = 0; qb < 4; ++qb)
        #pragma unroll
        for (int kb = 0; kb < 2; ++kb)
            qf[qb][kb] = *(const short8*)&Qh[(size_t)(q0 + qb * 16 + c) * 64 + kb * 32 + qd * 8];

    f32x4 o[4][4];
    float lsum[4];
    #pragma unroll
    for (int mt = 0; mt < 4; ++mt)
        #pragma unroll
        for (int qb = 0; qb < 4; ++qb) o[mt][qb] = f32x4{0.f, 0.f, 0.f, 0.f};
    #pragma unroll
    for (int qb = 0; qb < 4; ++qb) lsum[qb] = 0.f;

    #pragma unroll
    for (int j = 0; j < 2; ++j) {
        const int row = j * 8 + krow8;
        gload_lds16(Kh + (size_t)(w * 512 + row) * 64 + kgc * 8,
                    Kst + j * 512 + lane * 8);
    }
    short4v vA[4], vB[4];
    {
        const u16* vb = Vh + (size_t)(w * 32) * 1024 + voff;
        #pragma unroll
        for (int mt = 0; mt < 4; ++mt)
            vA[mt] = *(const short4v*)(vb + mt * 256);
    }
    #pragma unroll
    for (int j = 0; j < 2; ++j) {
        const int row = j * 8 + krow8;
        gload_lds16(Kh + (size_t)(w * 512 + 16 + row) * 64 + kgc * 8,
                    Kst + 1024 + j * 512 + lane * 8);
    }

    int cur = 0;
    auto body = [&](int it, short4v (&VC)[4], short4v (&VN)[4]) {
        u16* Kb = Kst + cur * 1024;

        __builtin_amdgcn_s_waitcnt(0xF74);   // vmcnt(4): K(it) staged
        __builtin_amdgcn_sched_barrier(0);

        short8 kf[2];
        #pragma unroll
        for (int kb = 0; kb < 2; ++kb)
            kf[kb] = *(const short8*)&Kb[c * 64 + ((4 * kb + qd) ^ (c & 7)) * 8];

        __builtin_amdgcn_sched_barrier(0);

        {
            const int itn = (it + 1) & 31;
            const u16* vb = Vh + (size_t)(w * 32 + itn) * 1024 + voff;
            #pragma unroll
            for (int mt = 0; mt < 4; ++mt)
                VN[mt] = *(const short4v*)(vb + mt * 256);
        }
        {
            const int itn = (it + 2) & 31;
            const int t0n = w * 512 + itn * 16;
            const int nslot = (cur >= 1) ? cur - 1 : 2;
            u16* Kn = Kst + nslot * 1024;
            #pragma unroll
            for (int j = 0; j < 2; ++j) {
                const int row = j * 8 + krow8;
                gload_lds16(Kh + (size_t)(t0n + row) * 64 + kgc * 8,
                            Kn + j * 512 + lane * 8);
            }
        }

        f32x4 sc[4];
        #pragma unroll
        for (int qb = 0; qb < 4; ++qb) {
            sc[qb] = f32x4{0.f, 0.f, 0.f, 0.f};
            sc[qb] = __builtin_amdgcn_mfma_f32_16x16x32_bf16(kf[0], qf[qb][0], sc[qb], 0, 0, 0);
            sc[qb] = __builtin_amdgcn_mfma_f32_16x16x32_bf16(kf[1], qf[qb][1], sc[qb], 0, 0, 0);
        }

        short4v pb[4];
        #pragma unroll
        for (int qb = 0; qb < 4; ++qb) {
            float p0 = fexp2(sc[qb][0]);
            float p1 = fexp2(sc[qb][1]);
            float p2 = fexp2(sc[qb][2]);
            float p3 = fexp2(sc[qb][3]);
            lsum[qb] += (p0 + p1) + (p2 + p3);
            unsigned d0 = pack_bf16(p0, p1);
            unsigned d1 = pack_bf16(p2, p3);
            union { unsigned u[2]; short4v s; } pu;
            pu.u[0] = d0; pu.u[1] = d1;
            pb[qb] = pu.s;
        }

        #pragma unroll
        for (int qb = 0; qb < 4; ++qb)
            #pragma unroll
            for (int mt = 0; mt < 4; ++mt)
                o[mt][qb] = mfma16(VC[mt], pb[qb], o[mt][qb]);

        cur = (cur == 2) ? 0 : cur + 1;
    };

    for (int it2 = 0; it2 < 16; ++it2) {
        body(2 * it2, vA, vB);
        body(2 * it2 + 1, vB, vA);
    }

    __builtin_amdgcn_s_waitcnt(0xF70);   // vmcnt(0) before aliasing the pool
    __syncthreads();

    #pragma unroll
    for (int qb = 0; qb < 4; ++qb) {
        lsum[qb] += __shfl_xor(lsum[qb], 16, 64);
        lsum[qb] += __shfl_xor(lsum[qb], 32, 64);
    }
    if (qd == 0) {
        #pragma unroll
        for (int qb = 0; qb < 4; ++qb) Ls[w][qb * 16 + c] = lsum[qb];
    }

    if (w >= 2) {
        float (*S)[66] = Os[w - 2];
        #pragma unroll
        for (int mt = 0; mt < 4; ++mt)
            #pragma unroll
            for (int qb = 0; qb < 4; ++qb)
                #pragma unroll
                for (int r = 0; r < 4; ++r)
                    S[mt * 16 + qd * 4 + r][qb * 16 + c] = o[mt][qb][r];
    }
    __syncthreads();
    if (w < 2) {
        float (*S)[66] = Os[w];
        #pragma unroll
        for (int mt = 0; mt < 4; ++mt)
            #pragma unroll
            for (int qb = 0; qb < 4; ++qb)
                #pragma unroll
                for (int r = 0; r < 4; ++r)
                    o[mt][qb][r] += S[mt * 16 + qd * 4 + r][qb * 16 + c];
    }
    __syncthreads();
    if (w == 1) {
        float (*S)[66] = Os[0];
        #pragma unroll
        for (int mt = 0; mt < 4; ++mt)
            #pragma unroll
            for (int qb = 0; qb < 4; ++qb)
                #pragma unroll
                for (int r = 0; r < 4; ++r)
                    S[mt * 16 + qd * 4 + r][qb * 16 + c] = o[mt][qb][r];
    }
    __syncthreads();
    if (w == 0) {
        float (*S)[66] = Os[0];
        float inv[4];
        #pragma unroll
        for (int qb = 0; qb < 4; ++qb) {
            int q = qb * 16 + c;
            float l = (Ls[0][q] + Ls[1][q]) + (Ls[2][q] + Ls[3][q]);
            inv[qb] = __builtin_amdgcn_rcpf(l);
        }
        #pragma unroll
        for (int mt = 0; mt < 4; ++mt)
            #pragma unroll
            for (int qb = 0; qb < 4; ++qb) {
                u16x4 ov;
                #pragma unroll
                for (int r = 0; r < 4; ++r) {
                    float v = (o[mt][qb][r] + S[mt * 16 + qd * 4 + r][qb * 16 + c]) * inv[qb];
                    ((u16*)&ov)[r] = f2bf(v);
                }
                *(u16x4*)&ctx[((size_t)(b * 2048 + q0 + qb * 16 + c)) * 1024
                              + h * 64 + mt * 16 + qd * 4] = ov;
            }
    }
}

// ---------------- output projection v2 (R9-proven verbatim) -------------------
__global__ __launch_bounds__(256, 4) void gemm_out_kernel(
    const u16* __restrict__ A, const u16* __restrict__ Wt,
    const float* __restrict__ bo, float* __restrict__ out)
{
    __shared__ __align__(16) u16 As[2][64 * 32];
    __shared__ __align__(16) u16 Bs[2][128 * 32];
    const int tid = threadIdx.x;
    const int lane = tid & 63;
    const int wv = tid >> 6;
    const int wm = wv & 1, wn = wv >> 1;
    const int c = lane & 15, qd = lane >> 4;

    const int id = (blockIdx.x & 7) * 64 + (blockIdx.x >> 3);
    const int m0 = (id >> 3) * 64;
    const int n0 = (id & 7) * 128;

    f32x4 acc[2][4];
    #pragma unroll
    for (int a = 0; a < 2; ++a)
        #pragma unroll
        for (int b2 = 0; b2 < 4; ++b2) acc[a][b2] = f32x4{0.f, 0.f, 0.f, 0.f};

    const u16* Ab = A + (size_t)m0 * 1024;
    const u16* Wb = Wt + (size_t)n0 * 1024;

    const int arow = tid >> 2, apart = tid & 3;

    auto stage = [&](int t, int p) {
        gload_lds16(Ab + (size_t)arow * 1024 + t * 32 + apart * 8, &As[p][tid * 8]);
        #pragma unroll
        for (int i = 0; i < 2; ++i) {
            int slot = i * 256 + tid;
            int row = slot >> 2, part = slot & 3;
            gload_lds16(Wb + (size_t)row * 1024 + t * 32 + part * 8, &Bs[p][slot * 8]);
        }
    };

    stage(0, 0);

    for (int t = 0; t < 32; ++t) {
        const int p = t & 1;
        if (t < 31) stage(t + 1, p ^ 1);
        __builtin_amdgcn_sched_barrier(0);
        if (t < 31) __builtin_amdgcn_s_waitcnt(0xF73);   // vmcnt(3): tile t landed
        else        __builtin_amdgcn_s_waitcnt(0xF70);   // last tile: drain
        SBAR();
        short8 af[2], bf[4];
        #pragma unroll
        for (int mt = 0; mt < 2; ++mt)
            af[mt] = *(const short8*)&As[p][(wm * 32 + mt * 16 + c) * 32 + qd * 8];
        #pragma unroll
        for (int nt = 0; nt < 4; ++nt)
            bf[nt] = *(const short8*)&Bs[p][(wn * 64 + nt * 16 + c) * 32 + qd * 8];
        __builtin_amdgcn_s_setprio(1);
        #pragma unroll
        for (int mt = 0; mt < 2; ++mt)
            #pragma unroll
            for (int nt = 0; nt < 4; ++nt)
                acc[mt][nt] = __builtin_amdgcn_mfma_f32_16x16x32_bf16(af[mt], bf[nt], acc[mt][nt], 0, 0, 0);
        __builtin_amdgcn_s_setprio(0);
        SBAR();   // all reads of buf p done before it is re-staged at t+2
    }

    #pragma unroll
    for (int mt = 0; mt < 2; ++mt) {
        const int mbase = m0 + wm * 32 + mt * 16 + qd * 4;
        #pragma unroll
        for (int nt = 0; nt < 4; ++nt) {
            const int n = n0 + wn * 64 + nt * 16 + c;
            const float bias = bo[n];
            #pragma unroll
            for (int r = 0; r < 4; ++r)
                out[(size_t)(mbase + r) * 1024 + n] = acc[mt][nt][r] + bias;
        }
    }
}

extern "C" void kernel_launch(void* const* d_in, const int* in_sizes, int n_in,
                              void* d_out, int out_size, void* d_ws, size_t ws_size,
                              hipStream_t stream) {
    const float* x  = (const float*)d_in[0];
    const float* Wq = (const float*)d_in[1];
    const float* bq = (const float*)d_in[2];
    const float* Wk = (const float*)d_in[3];
    const float* bk = (const float*)d_in[4];
    const float* Wv = (const float*)d_in[5];
    const float* bv = (const float*)d_in[6];
    const float* Wo = (const float*)d_in[7];
    const float* bo = (const float*)d_in[8];
    float* out = (float*)d_out;

    u16* ws    = (u16*)d_ws;
    u16* xb    = ws;                          // 4096*1024
    u16* wqkv  = xb + 4096 * 1024;            // 3072*1024
    u16* wot   = wqkv + 3072 * 1024;          // 1024*1024
    u16* qws   = wot + 1024 * 1024;           // 32*2048*64
    u16* kws   = qws + 4194304;               // 32*2048*64
    u16* v2ws  = kws + 4194304;               // 32*128*64*16
    u16* ctxws = v2ws + 4194304;              // 4096*1024

    prep_kernel<<<dim3(16, 16, 5), 256, 0, stream>>>(x, Wq, Wk, Wv, Wo, xb, wqkv, wot);
    gemm_qkv_kernel<<<256, 512, 0, stream>>>(xb, wqkv, bq, bk, bv, qws, kws, v2ws);
    flash_kernel<<<1024, 256, 0, stream>>>(qws, kws, v2ws, ctxws);
    gemm_out_kernel<<<512, 256, 0, stream>>>(ctxws, wot, bo, out);
}